// Round 2
// baseline (1027.522 us; speedup 1.0000x reference)
//
#include <hip/hip_runtime.h>
#include <hip/hip_bf16.h>
#include <math.h>

typedef __hip_bfloat16 bf16;
#define MEG 1048576

__device__ __forceinline__ float b2f(bf16 v) { return __bfloat162float(v); }
__device__ __forceinline__ float siluf(float x) { return x / (1.f + __expf(-x)); }

// Runtime dtype probe: ln1_g[0] == 1.0. As bf16 the first ushort is 0x3F80;
// as float32 the first ushort (little-endian low half of 1.0f) is 0x0000.
__device__ __forceinline__ int probe_bf16(const unsigned short* pr) {
    return pr[0] == 0x3F80;
}
__device__ __forceinline__ float ldw(const void* p, int i, int isb) {
    return isb ? __bfloat162float(((const bf16*)p)[i]) : ((const float*)p)[i];
}

// ---------------- LayerNorm over D=256, one block per row ----------------
// ln1: reads z (B,T,K,D layout), writes u in (BK,T,D) band-major layout
__global__ __launch_bounds__(256) void ln1_kernel(const void* __restrict__ z,
    const void* __restrict__ g, const void* __restrict__ b, float* __restrict__ u,
    const unsigned short* __restrict__ pr)
{
    int isb = probe_bf16(pr);
    int r = blockIdx.x;              // band row: bk*T + t
    int t = r & 255, bk = r >> 8;
    int b_ = bk >> 3, k = bk & 7;
    int src = ((b_ * 256 + t) * 8 + k) * 256;
    int d = threadIdx.x;
    float x = ldw(z, src + d, isb);
    __shared__ float lds[4];
    float v = x;
    #pragma unroll
    for (int off = 32; off; off >>= 1) v += __shfl_xor(v, off, 64);
    if ((threadIdx.x & 63) == 0) lds[threadIdx.x >> 6] = v;
    __syncthreads();
    float mean = (lds[0] + lds[1] + lds[2] + lds[3]) * (1.f / 256.f);
    __syncthreads();
    float c = x - mean;
    v = c * c;
    #pragma unroll
    for (int off = 32; off; off >>= 1) v += __shfl_xor(v, off, 64);
    if ((threadIdx.x & 63) == 0) lds[threadIdx.x >> 6] = v;
    __syncthreads();
    float var = (lds[0] + lds[1] + lds[2] + lds[3]) * (1.f / 256.f);
    u[r * 256 + d] = c * rsqrtf(var + 1e-5f) * ldw(g, d, isb) + ldw(b, d, isb);
}

// generic f32-in LN, identity row mapping
__global__ __launch_bounds__(256) void ln_f32_kernel(const float* __restrict__ zin,
    const void* __restrict__ g, const void* __restrict__ b, float* __restrict__ out,
    const unsigned short* __restrict__ pr)
{
    int isb = probe_bf16(pr);
    int r = blockIdx.x;
    int d = threadIdx.x;
    float x = zin[r * 256 + d];
    __shared__ float lds[4];
    float v = x;
    #pragma unroll
    for (int off = 32; off; off >>= 1) v += __shfl_xor(v, off, 64);
    if ((threadIdx.x & 63) == 0) lds[threadIdx.x >> 6] = v;
    __syncthreads();
    float mean = (lds[0] + lds[1] + lds[2] + lds[3]) * (1.f / 256.f);
    __syncthreads();
    float c = x - mean;
    v = c * c;
    #pragma unroll
    for (int off = 32; off; off >>= 1) v += __shfl_xor(v, off, 64);
    if ((threadIdx.x & 63) == 0) lds[threadIdx.x >> 6] = v;
    __syncthreads();
    float var = (lds[0] + lds[1] + lds[2] + lds[3]) * (1.f / 256.f);
    out[r * 256 + d] = c * rsqrtf(var + 1e-5f) * ldw(g, d, isb) + ldw(b, d, isb);
}

// ---------------- fp32 GEMM: C[M,N] = A[M,K] * B  (+bias)(+silu) ----------------
// transB=0: B is K x N row-major. transB=1: B is N x K row-major.
__global__ __launch_bounds__(256) void gemm_kernel(
    const float* __restrict__ A, const void* __restrict__ Bw,
    const void* __restrict__ bias, float* __restrict__ C,
    int M, int N, int Kd, int transB, int act,
    const unsigned short* __restrict__ pr)
{
    int isb = probe_bf16(pr);
    __shared__ float As[64][17];
    __shared__ float Bs[16][66];
    int tid = threadIdx.x;
    int tx = tid & 15, ty = tid >> 4;
    int n0 = blockIdx.x * 64, m0 = blockIdx.y * 64;
    float acc[4][4] = {};
    for (int k0 = 0; k0 < Kd; k0 += 16) {
        #pragma unroll
        for (int i = 0; i < 4; i++) {
            int idx = tid + i * 256;
            int mm = idx >> 4, kk = idx & 15;
            As[mm][kk] = A[(m0 + mm) * Kd + k0 + kk];
        }
        if (!transB) {
            #pragma unroll
            for (int i = 0; i < 4; i++) {
                int idx = tid + i * 256;
                int nn = idx & 63, kk = idx >> 6;
                int n = n0 + nn;
                Bs[kk][nn] = (n < N) ? ldw(Bw, (k0 + kk) * N + n, isb) : 0.f;
            }
        } else {
            #pragma unroll
            for (int i = 0; i < 4; i++) {
                int idx = tid + i * 256;
                int kk = idx & 15, nn = idx >> 4;
                int n = n0 + nn;
                Bs[kk][nn] = (n < N) ? ldw(Bw, n * Kd + k0 + kk, isb) : 0.f;
            }
        }
        __syncthreads();
        #pragma unroll
        for (int kk = 0; kk < 16; kk++) {
            float av[4], bv[4];
            #pragma unroll
            for (int i = 0; i < 4; i++) av[i] = As[ty * 4 + i][kk];
            #pragma unroll
            for (int j = 0; j < 4; j++) bv[j] = Bs[kk][tx * 4 + j];
            #pragma unroll
            for (int i = 0; i < 4; i++)
                #pragma unroll
                for (int j = 0; j < 4; j++) acc[i][j] += av[i] * bv[j];
        }
        __syncthreads();
    }
    #pragma unroll
    for (int i = 0; i < 4; i++) {
        int m = m0 + ty * 4 + i;
        #pragma unroll
        for (int j = 0; j < 4; j++) {
            int n = n0 + tx * 4 + j;
            if (n < N) {
                float v = acc[i][j];
                if (bias) v += ldw(bias, n, isb);
                if (act) v = siluf(v);
                C[m * N + n] = v;
            }
        }
    }
}

// ---------------- causal depthwise conv (kernel 4) + silu ----------------
__global__ __launch_bounds__(256) void conv_silu_kernel(const float* __restrict__ x,
    const void* __restrict__ w, float* __restrict__ out,
    const unsigned short* __restrict__ pr)
{
    int isb = probe_bf16(pr);
    int idx = blockIdx.x * 256 + threadIdx.x;   // (BK*T) * D
    int d = idx & 255;
    int r = idx >> 8;      // bk*T + t
    int t = r & 255;
    float acc = 0.f;
    #pragma unroll
    for (int kk = 0; kk < 4; kk++) {
        int tt = t + kk - 3;
        if (tt >= 0) acc += x[(r + kk - 3) * 256 + d] * ldw(w, d * 4 + kk, isb);
    }
    out[idx] = siluf(acc);
}

// ---------------- dt = softplus(raw + bias); ar/ai decay-rotation ----------------
__global__ __launch_bounds__(256) void dtprep_kernel(float* __restrict__ dt,
    float* __restrict__ ar, float* __restrict__ ai,
    const void* __restrict__ dt_bias, const void* __restrict__ A_log,
    const void* __restrict__ theta, const unsigned short* __restrict__ pr)
{
    int isb = probe_bf16(pr);
    int idx = blockIdx.x * 256 + threadIdx.x;  // R*H = 16384
    int h = idx & 3;
    float x = dt[idx] + ldw(dt_bias, h, isb);
    float d = (x > 20.f) ? x : log1pf(__expf(x));
    float A = -__expf(ldw(A_log, h, isb));
    float mag = __expf(d * A);
    float ph = d * ldw(theta, h, isb);
    dt[idx] = d;
    ar[idx] = mag * __cosf(ph);
    ai[idx] = mag * __sinf(ph);
}

// ---------------- MIMO cross-head mixing of B (in place) ----------------
__global__ __launch_bounds__(256) void mix_kernel(float* __restrict__ Bm,
    const void* __restrict__ U, const void* __restrict__ V,
    const unsigned short* __restrict__ pr)
{
    int isb = probe_bf16(pr);
    int idx = blockIdx.x * 256 + threadIdx.x;   // R * N = 4096*128
    int n = idx & 127, r = idx >> 7;
    float Mm[4][4];
    #pragma unroll
    for (int h = 0; h < 4; h++)
        #pragma unroll
        for (int g = 0; g < 4; g++) {
            float s = 0.f;
            #pragma unroll
            for (int j = 0; j < 4; j++) s += ldw(U, h * 4 + j, isb) * ldw(V, g * 4 + j, isb);
            Mm[h][g] = s;
        }
    float in[4];
    #pragma unroll
    for (int g = 0; g < 4; g++) in[g] = Bm[r * 512 + g * 128 + n];
    #pragma unroll
    for (int h = 0; h < 4; h++) {
        float s = 0.f;
        #pragma unroll
        for (int g = 0; g < 4; g++) s += Mm[h][g] * in[g];
        Bm[r * 512 + h * 128 + n] = s;
    }
}

// ---------------- complex MIMO selective scan: one block per (bk,h) ----------------
__global__ __launch_bounds__(512) void scan_kernel(
    const float* __restrict__ xh, const float* __restrict__ Bm,
    const float* __restrict__ Cm, const float* __restrict__ dt,
    const float* __restrict__ ar, const float* __restrict__ ai,
    const void* __restrict__ D_skip, float* __restrict__ y,
    const unsigned short* __restrict__ pr)
{
    int isb = probe_bf16(pr);
    int bk = blockIdx.x >> 2, h = blockIdx.x & 3;
    int tid = threadIdx.x;
    int p = tid & 63, g = tid >> 6;     // g in [0,8), 16 n's each
    __shared__ float xs[64], bs[128], cs[128], red[512], scal[3];
    float hre[16] = {}, him[16] = {};
    float dsk = ldw(D_skip, h, isb);
    int nb = g * 16;
    for (int t = 0; t < 256; t++) {
        int r = bk * 256 + t;
        if (tid < 64)       xs[tid] = xh[r * 256 + h * 64 + tid];
        else if (tid < 192) bs[tid - 64]  = Bm[r * 512 + h * 128 + (tid - 64)];
        else if (tid < 320) cs[tid - 192] = Cm[r * 512 + h * 128 + (tid - 192)];
        else if (tid == 320) scal[0] = dt[r * 4 + h];
        else if (tid == 321) scal[1] = ar[r * 4 + h];
        else if (tid == 322) scal[2] = ai[r * 4 + h];
        __syncthreads();
        float xv = xs[p], dts = scal[0], arr = scal[1], aii = scal[2];
        float partial = 0.f;
        #pragma unroll
        for (int i = 0; i < 16; i++) {
            float bv = bs[nb + i];
            float hr = hre[i], hi = him[i];
            float nr = arr * hr - aii * hi + dts * bv * xv;
            float ni = arr * hi + aii * hr;
            hre[i] = nr; him[i] = ni;
            partial += cs[nb + i] * nr;
        }
        red[g * 64 + p] = partial;
        __syncthreads();
        if (tid < 64) {
            float yv = 0.f;
            #pragma unroll
            for (int q = 0; q < 8; q++) yv += red[q * 64 + tid];
            y[r * 256 + h * 64 + tid] = yv + dsk * xs[tid];
        }
        __syncthreads();
    }
}

// ---------------- elementwise helpers ----------------
__global__ __launch_bounds__(256) void mul_kernel(float* __restrict__ y, const float* __restrict__ zg)
{
    int i = blockIdx.x * 256 + threadIdx.x;
    y[i] *= zg[i];
}

// z1[b,t,k,d] = z + yout[band-major]
__global__ __launch_bounds__(256) void addres_kernel(const void* __restrict__ z,
    const float* __restrict__ yout, float* __restrict__ z1,
    const unsigned short* __restrict__ pr)
{
    int isb = probe_bf16(pr);
    int idx = blockIdx.x * 256 + threadIdx.x;
    int d = idx & 255;
    int rt = idx >> 8;
    int k = rt & 7, bt = rt >> 3;
    int t = bt & 255, b = bt >> 8;
    int rb = (b * 8 + k) * 256 + t;
    z1[idx] = ldw(z, idx, isb) + yout[rb * 256 + d];
}

__global__ __launch_bounds__(256) void add_kernel(const float* __restrict__ a,
    const float* __restrict__ b, float* __restrict__ c)
{
    int i = blockIdx.x * 256 + threadIdx.x;
    c[i] = a[i] + b[i];
}

__global__ __launch_bounds__(256) void glu_kernel(float* __restrict__ g, const float* __restrict__ uu)
{
    int i = blockIdx.x * 256 + threadIdx.x;
    g[i] = siluf(g[i]) * uu[i];
}

__global__ __launch_bounds__(256) void final_kernel(const float* __restrict__ z2,
    const float* __restrict__ ffn, void* __restrict__ out,
    const unsigned short* __restrict__ pr)
{
    int isb = probe_bf16(pr);
    int i = blockIdx.x * 256 + threadIdx.x;
    float v = z2[i] + ffn[i];
    if (isb) ((bf16*)out)[i] = __float2bfloat16(v);
    else     ((float*)out)[i] = v;
}

// ---------------- windowed attention: one block per (token m, window w) ----------------
__global__ __launch_bounds__(256) void attn_kernel(const float* __restrict__ qkv,
    float* __restrict__ o)
{
    int m = blockIdx.x >> 1, w = blockIdx.x & 1;
    int tid = threadIdx.x;
    int h = tid >> 6, d = tid & 63;     // wave = head
    __shared__ float qs[4][256], ks[4][256], vs[4][256];
    #pragma unroll
    for (int j = 0; j < 4; j++) {
        int row = m * 8 + w * 4 + j;
        int base = row * 768;
        qs[j][tid] = qkv[base + tid];
        ks[j][tid] = qkv[base + 256 + tid];
        vs[j][tid] = qkv[base + 512 + tid];
    }
    __syncthreads();
    float sc[4][4];
    #pragma unroll
    for (int qi = 0; qi < 4; qi++)
        #pragma unroll
        for (int ki = 0; ki < 4; ki++) {
            float v = qs[qi][h * 64 + d] * ks[ki][h * 64 + d];
            #pragma unroll
            for (int off = 32; off; off >>= 1) v += __shfl_xor(v, off, 64);
            sc[qi][ki] = v * 0.125f;
        }
    #pragma unroll
    for (int qi = 0; qi < 4; qi++) {
        float mx = fmaxf(fmaxf(sc[qi][0], sc[qi][1]), fmaxf(sc[qi][2], sc[qi][3]));
        float e0 = __expf(sc[qi][0] - mx), e1 = __expf(sc[qi][1] - mx);
        float e2 = __expf(sc[qi][2] - mx), e3 = __expf(sc[qi][3] - mx);
        float inv = 1.f / (e0 + e1 + e2 + e3);
        float ov = (e0 * vs[0][h * 64 + d] + e1 * vs[1][h * 64 + d] +
                    e2 * vs[2][h * 64 + d] + e3 * vs[3][h * 64 + d]) * inv;
        o[(m * 8 + w * 4 + qi) * 256 + h * 64 + d] = ov;
    }
}

extern "C" void kernel_launch(void* const* d_in, const int* in_sizes, int n_in,
                              void* d_out, int out_size, void* d_ws, size_t ws_size,
                              hipStream_t stream)
{
    const void* z         = d_in[0];
    const void* ln1_g     = d_in[1];
    const void* ln1_b     = d_in[2];
    const void* Wx        = d_in[3];
    const void* conv_w    = d_in[4];
    const void* Wz        = d_in[5];
    const void* Wb        = d_in[6];
    const void* Wc        = d_in[7];
    const void* Wdt       = d_in[8];
    const void* dt_bias   = d_in[9];
    const void* A_log     = d_in[10];
    const void* theta     = d_in[11];
    const void* D_skip    = d_in[12];
    const void* mimo_U    = d_in[13];
    const void* mimo_V    = d_in[14];
    const void* Wout      = d_in[15];
    const void* ln2_g     = d_in[16];
    const void* ln2_b     = d_in[17];
    const void* attn_in_w = d_in[18];
    const void* attn_in_b = d_in[19];
    const void* attn_out_w= d_in[20];
    const void* attn_out_b= d_in[21];
    const void* ln3_g     = d_in[22];
    const void* ln3_b     = d_in[23];
    const void* Wg        = d_in[24];
    const void* Wu        = d_in[25];
    const void* Wd        = d_in[26];
    const unsigned short* pr = (const unsigned short*)d_in[1];  // ln1_g == ones

    float* W  = (float*)d_ws;
    // part (a) buffers
    float* u   = W;                      // 1M
    float* x   = W + 1 * MEG;            // 1M
    float* Bm  = W + 2 * MEG;            // 2M
    float* Cm  = W + 4 * MEG;            // 2M
    float* dt  = W + 6 * MEG;            // 16K
    float* ar  = dt + 16384;             // 16K
    float* ai  = ar + 16384;             // 16K
    float* zg  = W + 6 * MEG + 65536;    // 1M
    float* y   = W + 7 * MEG + 65536;    // 1M
    float* z1  = W + 8 * MEG + 65536;    // 1M (lives until z2)
    float* x2  = W + 9 * MEG + 65536;    // 1M (xh after conv)
    // reuse regions (lifetimes disjoint)
    float* t0  = W;                      // yout -> zn -> o2 -> zf -> ffn (1M)
    float* qkv = W + 1 * MEG;            // 3M
    float* o   = W + 4 * MEG;            // 1M
    float* z2  = W + 5 * MEG;            // 1M (lives until end)
    float* gg  = W + 1 * MEG;            // 4M (FFN gate, after qkv dead)
    float* uu  = W + 6 * MEG + 65536;    // 4M

    // ---------------- part (a): intra-band Mamba3 ----------------
    ln1_kernel<<<4096, 256, 0, stream>>>(z, ln1_g, ln1_b, u, pr);
    gemm_kernel<<<dim3(4, 64), 256, 0, stream>>>(u, Wx, nullptr, x, 4096, 256, 256, 0, 0, pr);
    conv_silu_kernel<<<4096, 256, 0, stream>>>(x, conv_w, x2, pr);
    gemm_kernel<<<dim3(8, 64), 256, 0, stream>>>(u, Wb, nullptr, Bm, 4096, 512, 256, 0, 0, pr);
    gemm_kernel<<<dim3(8, 64), 256, 0, stream>>>(u, Wc, nullptr, Cm, 4096, 512, 256, 0, 0, pr);
    gemm_kernel<<<dim3(1, 64), 256, 0, stream>>>(u, Wdt, nullptr, dt, 4096, 4, 256, 0, 0, pr);
    gemm_kernel<<<dim3(4, 64), 256, 0, stream>>>(u, Wz, nullptr, zg, 4096, 256, 256, 0, 1, pr);
    dtprep_kernel<<<64, 256, 0, stream>>>(dt, ar, ai, dt_bias, A_log, theta, pr);
    mix_kernel<<<2048, 256, 0, stream>>>(Bm, mimo_U, mimo_V, pr);
    scan_kernel<<<64, 512, 0, stream>>>(x2, Bm, Cm, dt, ar, ai, D_skip, y, pr);
    mul_kernel<<<4096, 256, 0, stream>>>(y, zg);
    gemm_kernel<<<dim3(4, 64), 256, 0, stream>>>(y, Wout, nullptr, t0, 4096, 256, 256, 0, 0, pr);
    addres_kernel<<<4096, 256, 0, stream>>>(z, t0, z1, pr);
    // ---------------- part (b): inter-band windowed attention ----------------
    ln_f32_kernel<<<4096, 256, 0, stream>>>(z1, ln2_g, ln2_b, t0, pr);             // zn
    gemm_kernel<<<dim3(12, 64), 256, 0, stream>>>(t0, attn_in_w, attn_in_b, qkv, 4096, 768, 256, 1, 0, pr);
    attn_kernel<<<1024, 256, 0, stream>>>(qkv, o);
    gemm_kernel<<<dim3(4, 64), 256, 0, stream>>>(o, attn_out_w, attn_out_b, t0, 4096, 256, 256, 1, 0, pr);
    add_kernel<<<4096, 256, 0, stream>>>(z1, t0, z2);
    // ---------------- part (c): SwiGLU FFN ----------------
    ln_f32_kernel<<<4096, 256, 0, stream>>>(z2, ln3_g, ln3_b, t0, pr);             // zf
    gemm_kernel<<<dim3(16, 64), 256, 0, stream>>>(t0, Wg, nullptr, gg, 4096, 1024, 256, 0, 0, pr);
    gemm_kernel<<<dim3(16, 64), 256, 0, stream>>>(t0, Wu, nullptr, uu, 4096, 1024, 256, 0, 0, pr);
    glu_kernel<<<16384, 256, 0, stream>>>(gg, uu);
    gemm_kernel<<<dim3(4, 64), 256, 0, stream>>>(gg, Wd, nullptr, t0, 4096, 256, 1024, 0, 0, pr);
    final_kernel<<<4096, 256, 0, stream>>>(z2, t0, (bf16*)d_out, pr);
}

// Round 3
// 410.741 us; speedup vs baseline: 2.5016x; 2.5016x over previous
//
#include <hip/hip_runtime.h>
#include <hip/hip_bf16.h>
#include <math.h>

typedef __hip_bfloat16 bf16;
typedef __attribute__((ext_vector_type(8))) short s16x8;
typedef __attribute__((ext_vector_type(4))) float f32x4;

__device__ __forceinline__ float siluf(float x) { return x / (1.f + __expf(-x)); }
__device__ __forceinline__ float bits2f(unsigned short u) {
    union { float f; unsigned i; } v; v.i = ((unsigned)u) << 16; return v.f;
}
__device__ __forceinline__ unsigned short f2bits(float f) {
    return (unsigned short)__bfloat16_as_ushort(__float2bfloat16(f));
}

// ---------------- workspace offsets (float units) ----------------
#define KFL 1024
#define OFF_WTS  0
#define OFF_UB   (768*KFL)
#define OFF_X2B  (1280*KFL)
#define OFF_BMB  (1792*KFL)
#define OFF_CMB  (2816*KFL)
#define OFF_DT   (3840*KFL)
#define OFF_AR   (3856*KFL)
#define OFF_AI   (3872*KFL)
#define OFF_ZG   (3888*KFL)
#define OFF_Y    (4912*KFL)
#define OFF_SH2  (5936*KFL)
#define OFF_Z2   (7984*KFL)
#define OFF_YGB  OFF_UB
#define OFF_YOUT OFF_ZG
#define OFF_Z1   OFF_BMB
#define OFF_ZNB  OFF_CMB
#define OFF_OB   (3328*KFL)
#define OFF_T0   OFF_ZG
#define OFF_QKV  OFF_Y
#define OFF_ZFB  OFF_UB
#define OFF_SGB  OFF_BMB
#define OFF_GGB  OFF_Y

// weight element offsets (bf16 elements, from ws base)
#define W_X    0
#define W_B    65536
#define W_C    196608
#define W_Z    327680
#define W_O    393216
#define W_QKV  458752
#define W_AO   655360
#define W_G    720896
#define W_U    983040
#define W_D    1245184

// ---------------- fused weight prep: fp32 -> bf16 (+transpose K x N -> N x K) --------
__global__ __launch_bounds__(256) void prep_w(
    const float* __restrict__ Wx, const float* __restrict__ Wb,
    const float* __restrict__ Wc, const float* __restrict__ Wz,
    const float* __restrict__ Wo, const float* __restrict__ Wqkv,
    const float* __restrict__ Wao, const float* __restrict__ Wg,
    const float* __restrict__ Wu, const float* __restrict__ Wd,
    unsigned short* __restrict__ out)
{
    int b = blockIdx.x;
    const float* src; int dst, kshift, Nn, trans, segb;
    if      (b < 256)  { src=Wx;   dst=W_X;   kshift=8;  Nn=256;  trans=1; segb=0; }
    else if (b < 768)  { src=Wb;   dst=W_B;   kshift=8;  Nn=512;  trans=1; segb=256; }
    else if (b < 1280) { src=Wc;   dst=W_C;   kshift=8;  Nn=512;  trans=1; segb=768; }
    else if (b < 1536) { src=Wz;   dst=W_Z;   kshift=8;  Nn=256;  trans=1; segb=1280; }
    else if (b < 1792) { src=Wo;   dst=W_O;   kshift=8;  Nn=256;  trans=1; segb=1536; }
    else if (b < 2560) { src=Wqkv; dst=W_QKV; kshift=8;  Nn=256;  trans=0; segb=1792; }
    else if (b < 2816) { src=Wao;  dst=W_AO;  kshift=8;  Nn=256;  trans=0; segb=2560; }
    else if (b < 3840) { src=Wg;   dst=W_G;   kshift=8;  Nn=1024; trans=1; segb=2816; }
    else if (b < 4864) { src=Wu;   dst=W_U;   kshift=8;  Nn=1024; trans=1; segb=3840; }
    else               { src=Wd;   dst=W_D;   kshift=10; Nn=256;  trans=1; segb=4864; }
    int idx = (b - segb) * 256 + threadIdx.x;
    float v;
    if (trans) {
        int n = idx >> kshift, k = idx & ((1 << kshift) - 1);
        v = src[k * Nn + n];
    } else {
        v = src[idx];
    }
    out[dst + idx] = f2bits(v);
}

// ---------------- LN1: z (B,T,K,D) fp32 -> u bf16 band-major (BK,T,D) ----------------
__global__ __launch_bounds__(256) void ln1_kernel(const float* __restrict__ z,
    const float* __restrict__ g, const float* __restrict__ b,
    unsigned short* __restrict__ u)
{
    int r = blockIdx.x;
    int t = r & 255, bk = r >> 8;
    int b_ = bk >> 3, k = bk & 7;
    int src = ((b_ * 256 + t) * 8 + k) * 256;
    int d = threadIdx.x;
    float x = z[src + d];
    __shared__ float lds[4];
    float v = x;
    #pragma unroll
    for (int off = 32; off; off >>= 1) v += __shfl_xor(v, off, 64);
    if ((threadIdx.x & 63) == 0) lds[threadIdx.x >> 6] = v;
    __syncthreads();
    float mean = (lds[0] + lds[1] + lds[2] + lds[3]) * (1.f / 256.f);
    __syncthreads();
    float c = x - mean;
    v = c * c;
    #pragma unroll
    for (int off = 32; off; off >>= 1) v += __shfl_xor(v, off, 64);
    if ((threadIdx.x & 63) == 0) lds[threadIdx.x >> 6] = v;
    __syncthreads();
    float var = (lds[0] + lds[1] + lds[2] + lds[3]) * (1.f / 256.f);
    u[r * 256 + d] = f2bits(c * rsqrtf(var + 1e-5f) * g[d] + b[d]);
}

// generic f32-in LN -> bf16 out, identity row mapping
__global__ __launch_bounds__(256) void ln_f32_kernel(const float* __restrict__ zin,
    const float* __restrict__ g, const float* __restrict__ b,
    unsigned short* __restrict__ out)
{
    int r = blockIdx.x;
    int d = threadIdx.x;
    float x = zin[r * 256 + d];
    __shared__ float lds[4];
    float v = x;
    #pragma unroll
    for (int off = 32; off; off >>= 1) v += __shfl_xor(v, off, 64);
    if ((threadIdx.x & 63) == 0) lds[threadIdx.x >> 6] = v;
    __syncthreads();
    float mean = (lds[0] + lds[1] + lds[2] + lds[3]) * (1.f / 256.f);
    __syncthreads();
    float c = x - mean;
    v = c * c;
    #pragma unroll
    for (int off = 32; off; off >>= 1) v += __shfl_xor(v, off, 64);
    if ((threadIdx.x & 63) == 0) lds[threadIdx.x >> 6] = v;
    __syncthreads();
    float var = (lds[0] + lds[1] + lds[2] + lds[3]) * (1.f / 256.f);
    out[r * 256 + d] = f2bits(c * rsqrtf(var + 1e-5f) * g[d] + b[d]);
}

// ---------------- MFMA bf16 GEMM: C[M,N] = A[M,K] @ Bt[N,K]^T (+bias)(+silu)(*mulin) --
// A, Bt bf16 row-major. Tile 128x128, BK=32, 4 waves. M=4096 fixed multiple of 128.
__global__ __launch_bounds__(256) void mfma_gemm(
    const unsigned short* __restrict__ A, const unsigned short* __restrict__ Bt,
    const float* __restrict__ bias, const unsigned short* __restrict__ mulin,
    void* __restrict__ C, int N, int K, int act, int out_bf16)
{
    __shared__ unsigned short As[128 * 40];
    __shared__ unsigned short Bs[128 * 40];
    int tid = threadIdx.x;
    int n0 = blockIdx.x * 128, m0 = blockIdx.y * 128;
    int w = tid >> 6, l = tid & 63;
    int mwave = (w >> 1) * 64, nwave = (w & 1) * 64;
    f32x4 zero = {0.f, 0.f, 0.f, 0.f};
    f32x4 acc[4][4];
    #pragma unroll
    for (int i = 0; i < 4; i++)
        #pragma unroll
        for (int j = 0; j < 4; j++) acc[i][j] = zero;
    int srow = tid >> 2, sc = (tid & 3) * 8;
    const unsigned short* Ap = A + (m0 + srow) * K + sc;
    const unsigned short* Bp = Bt + (n0 + srow) * K + sc;
    int lq = l & 15, lh = l >> 4;
    int ko = lh * 8;
    for (int k0 = 0; k0 < K; k0 += 32) {
        uint4 a0 = *(const uint4*)(Ap + k0);
        uint4 a1 = *(const uint4*)(Ap + 64 * K + k0);
        uint4 b0 = *(const uint4*)(Bp + k0);
        uint4 b1 = *(const uint4*)(Bp + 64 * K + k0);
        if (k0) __syncthreads();
        *(uint4*)&As[srow * 40 + sc] = a0;
        *(uint4*)&As[(srow + 64) * 40 + sc] = a1;
        *(uint4*)&Bs[srow * 40 + sc] = b0;
        *(uint4*)&Bs[(srow + 64) * 40 + sc] = b1;
        __syncthreads();
        s16x8 bfr[4];
        #pragma unroll
        for (int nf = 0; nf < 4; nf++)
            bfr[nf] = *(const s16x8*)&Bs[(nwave + nf * 16 + lq) * 40 + ko];
        #pragma unroll
        for (int mf = 0; mf < 4; mf++) {
            s16x8 af = *(const s16x8*)&As[(mwave + mf * 16 + lq) * 40 + ko];
            #pragma unroll
            for (int nf = 0; nf < 4; nf++)
                acc[mf][nf] = __builtin_amdgcn_mfma_f32_16x16x32_bf16(af, bfr[nf], acc[mf][nf], 0, 0, 0);
        }
    }
    #pragma unroll
    for (int mf = 0; mf < 4; mf++) {
        #pragma unroll
        for (int nf = 0; nf < 4; nf++) {
            int n = n0 + nwave + nf * 16 + lq;
            float bs_ = bias ? bias[n] : 0.f;
            #pragma unroll
            for (int r = 0; r < 4; r++) {
                int m = m0 + mwave + mf * 16 + lh * 4 + r;
                float v = acc[mf][nf][r] + bs_;
                if (act) v = siluf(v);
                if (mulin) v *= bits2f(mulin[m * N + n]);
                if (out_bf16) ((unsigned short*)C)[m * N + n] = f2bits(v);
                else          ((float*)C)[m * N + n] = v;
            }
        }
    }
}

// ---------------- dt_raw = u_b @ Wdt  (N=4), one wave per row ----------------
__global__ __launch_bounds__(64) void dt_small(const unsigned short* __restrict__ ub,
    const float* __restrict__ Wdt, float* __restrict__ dtout)
{
    int r = blockIdx.x, l = threadIdx.x;
    ushort4 uv = *(const ushort4*)(ub + r * 256 + l * 4);
    float u0 = bits2f(uv.x), u1 = bits2f(uv.y), u2 = bits2f(uv.z), u3 = bits2f(uv.w);
    float4 w0 = *(const float4*)(Wdt + (l * 4 + 0) * 4);
    float4 w1 = *(const float4*)(Wdt + (l * 4 + 1) * 4);
    float4 w2 = *(const float4*)(Wdt + (l * 4 + 2) * 4);
    float4 w3 = *(const float4*)(Wdt + (l * 4 + 3) * 4);
    float p0 = u0 * w0.x + u1 * w1.x + u2 * w2.x + u3 * w3.x;
    float p1 = u0 * w0.y + u1 * w1.y + u2 * w2.y + u3 * w3.y;
    float p2 = u0 * w0.z + u1 * w1.z + u2 * w2.z + u3 * w3.z;
    float p3 = u0 * w0.w + u1 * w1.w + u2 * w2.w + u3 * w3.w;
    #pragma unroll
    for (int off = 32; off; off >>= 1) {
        p0 += __shfl_xor(p0, off, 64);
        p1 += __shfl_xor(p1, off, 64);
        p2 += __shfl_xor(p2, off, 64);
        p3 += __shfl_xor(p3, off, 64);
    }
    if (l == 0) {
        dtout[r * 4 + 0] = p0; dtout[r * 4 + 1] = p1;
        dtout[r * 4 + 2] = p2; dtout[r * 4 + 3] = p3;
    }
}

// ---------------- causal depthwise conv (k=4) + silu, fp32 in -> bf16 out --------
__global__ __launch_bounds__(256) void conv_silu_kernel(const float* __restrict__ x,
    const float* __restrict__ w, unsigned short* __restrict__ out)
{
    int idx = blockIdx.x * 256 + threadIdx.x;
    int d = idx & 255;
    int r = idx >> 8;
    int t = r & 255;
    float acc = 0.f;
    #pragma unroll
    for (int kk = 0; kk < 4; kk++) {
        int tt = t + kk - 3;
        if (tt >= 0) acc += x[(r + kk - 3) * 256 + d] * w[d * 4 + kk];
    }
    out[idx] = f2bits(siluf(acc));
}

// ---------------- dt = softplus(raw+bias); ar/ai ----------------
__global__ __launch_bounds__(256) void dtprep_kernel(float* __restrict__ dt,
    float* __restrict__ ar, float* __restrict__ ai,
    const float* __restrict__ dt_bias, const float* __restrict__ A_log,
    const float* __restrict__ theta)
{
    int idx = blockIdx.x * 256 + threadIdx.x;
    int h = idx & 3;
    float x = dt[idx] + dt_bias[h];
    float d = (x > 20.f) ? x : log1pf(__expf(x));
    float A = -__expf(A_log[h]);
    float mag = __expf(d * A);
    float ph = d * theta[h];
    dt[idx] = d;
    ar[idx] = mag * __cosf(ph);
    ai[idx] = mag * __sinf(ph);
}

// ---------------- MIMO mix: Bm32 fp32 -> Bm_b bf16 ----------------
__global__ __launch_bounds__(256) void mix_kernel(const float* __restrict__ Bm,
    const float* __restrict__ U, const float* __restrict__ V,
    unsigned short* __restrict__ Bb)
{
    int idx = blockIdx.x * 256 + threadIdx.x;
    int n = idx & 127, r = idx >> 7;
    float Mm[4][4];
    #pragma unroll
    for (int h = 0; h < 4; h++)
        #pragma unroll
        for (int g = 0; g < 4; g++) {
            float s = 0.f;
            #pragma unroll
            for (int j = 0; j < 4; j++) s += U[h * 4 + j] * V[g * 4 + j];
            Mm[h][g] = s;
        }
    float in[4];
    #pragma unroll
    for (int g = 0; g < 4; g++) in[g] = Bm[r * 512 + g * 128 + n];
    #pragma unroll
    for (int h = 0; h < 4; h++) {
        float s = 0.f;
        #pragma unroll
        for (int g = 0; g < 4; g++) s += Mm[h][g] * in[g];
        Bb[r * 512 + h * 128 + n] = f2bits(s);
    }
}

// ---------------- selective scan: wave-synchronous, p-split ----------------
// 1024 blocks x 64 threads. block -> (scan = b>>4, pgrp = b&15); scan -> (bk, h).
// lane: p = pgrp*4 + (l>>4); n-set = (l&15)*8 .. +8. Ring-4 register prefetch.
__global__ __launch_bounds__(64) void scan2_kernel(
    const unsigned short* __restrict__ xb, const unsigned short* __restrict__ Bb,
    const unsigned short* __restrict__ Cb, const float* __restrict__ dt,
    const float* __restrict__ ar, const float* __restrict__ ai,
    const float* __restrict__ Dsk, float* __restrict__ y)
{
    int blk = blockIdx.x;
    int scan = blk >> 4, pg = blk & 15;
    int bk = scan >> 2, h = scan & 3;
    int l = threadIdx.x;
    int pp = l >> 4, q = l & 15;
    int p = pg * 4 + pp;
    int rbase = bk * 256;
    const unsigned short* bptr = Bb + rbase * 512 + h * 128 + q * 8;
    const unsigned short* cptr = Cb + rbase * 512 + h * 128 + q * 8;
    const unsigned short* xptr = xb + rbase * 256 + h * 64 + p;
    const float* sdt = dt + rbase * 4 + h;
    const float* sar = ar + rbase * 4 + h;
    const float* sai = ai + rbase * 4 + h;
    float dsk = Dsk[h];
    float hre[8] = {0,0,0,0,0,0,0,0}, him[8] = {0,0,0,0,0,0,0,0};
    uint4 pbv[4], pcv[4];
    float pdt[4], par[4], pai[4], pxv[4];
    #pragma unroll
    for (int i = 0; i < 4; i++) {
        pbv[i] = *(const uint4*)(bptr + i * 512);
        pcv[i] = *(const uint4*)(cptr + i * 512);
        pxv[i] = bits2f(xptr[i * 256]);
        pdt[i] = sdt[i * 4]; par[i] = sar[i * 4]; pai[i] = sai[i * 4];
    }
    #pragma unroll 4
    for (int t = 0; t < 256; t++) {
        int s = t & 3;
        uint4 bv = pbv[s], cv = pcv[s];
        float dts = pdt[s], arr = par[s], aii = pai[s], xv = pxv[s];
        int tn = t + 4; if (tn > 255) tn = 255;
        pbv[s] = *(const uint4*)(bptr + tn * 512);
        pcv[s] = *(const uint4*)(cptr + tn * 512);
        pxv[s] = bits2f(xptr[tn * 256]);
        pdt[s] = sdt[tn * 4]; par[s] = sar[tn * 4]; pai[s] = sai[tn * 4];
        float coef = dts * xv;
        const unsigned short* bu = (const unsigned short*)&bv;
        const unsigned short* cu = (const unsigned short*)&cv;
        float partial = 0.f;
        #pragma unroll
        for (int j = 0; j < 8; j++) {
            float bj = bits2f(bu[j]);
            float cj = bits2f(cu[j]);
            float hr = hre[j], hi = him[j];
            float nr = arr * hr - aii * hi + coef * bj;
            float ni = arr * hi + aii * hr;
            hre[j] = nr; him[j] = ni;
            partial += cj * nr;
        }
        partial += __shfl_xor(partial, 1, 64);
        partial += __shfl_xor(partial, 2, 64);
        partial += __shfl_xor(partial, 4, 64);
        partial += __shfl_xor(partial, 8, 64);
        if (q == 0)
            y[(rbase + t) * 256 + h * 64 + p] = partial + dsk * xv;
    }
}

// ---------------- elementwise ----------------
__global__ __launch_bounds__(256) void mul_kernel(const float* __restrict__ y,
    const float* __restrict__ zg, unsigned short* __restrict__ ygb)
{
    int i = blockIdx.x * 256 + threadIdx.x;
    ygb[i] = f2bits(y[i] * zg[i]);
}

__global__ __launch_bounds__(256) void addres_kernel(const float* __restrict__ z,
    const float* __restrict__ yout, float* __restrict__ z1)
{
    int idx = blockIdx.x * 256 + threadIdx.x;
    int d = idx & 255;
    int rt = idx >> 8;
    int k = rt & 7, bt = rt >> 3;
    int t = bt & 255, b = bt >> 8;
    int rb = (b * 8 + k) * 256 + t;
    z1[idx] = z[idx] + yout[rb * 256 + d];
}

__global__ __launch_bounds__(256) void add_kernel(const float* __restrict__ a,
    const float* __restrict__ b, float* __restrict__ c)
{
    int i = blockIdx.x * 256 + threadIdx.x;
    c[i] = a[i] + b[i];
}

__global__ __launch_bounds__(256) void final_kernel(const float* __restrict__ z2,
    const float* __restrict__ ffn, float* __restrict__ out)
{
    int i = blockIdx.x * 256 + threadIdx.x;
    out[i] = z2[i] + ffn[i];
}

// ---------------- windowed attention ----------------
__global__ __launch_bounds__(256) void attn_kernel(const float* __restrict__ qkv,
    unsigned short* __restrict__ o)
{
    int m = blockIdx.x >> 1, w = blockIdx.x & 1;
    int tid = threadIdx.x;
    int h = tid >> 6, d = tid & 63;
    __shared__ float qs[4][256], ks[4][256], vs[4][256];
    #pragma unroll
    for (int j = 0; j < 4; j++) {
        int row = m * 8 + w * 4 + j;
        int base = row * 768;
        qs[j][tid] = qkv[base + tid];
        ks[j][tid] = qkv[base + 256 + tid];
        vs[j][tid] = qkv[base + 512 + tid];
    }
    __syncthreads();
    float sc[4][4];
    #pragma unroll
    for (int qi = 0; qi < 4; qi++)
        #pragma unroll
        for (int ki = 0; ki < 4; ki++) {
            float v = qs[qi][h * 64 + d] * ks[ki][h * 64 + d];
            #pragma unroll
            for (int off = 32; off; off >>= 1) v += __shfl_xor(v, off, 64);
            sc[qi][ki] = v * 0.125f;
        }
    #pragma unroll
    for (int qi = 0; qi < 4; qi++) {
        float mx = fmaxf(fmaxf(sc[qi][0], sc[qi][1]), fmaxf(sc[qi][2], sc[qi][3]));
        float e0 = __expf(sc[qi][0] - mx), e1 = __expf(sc[qi][1] - mx);
        float e2 = __expf(sc[qi][2] - mx), e3 = __expf(sc[qi][3] - mx);
        float inv = 1.f / (e0 + e1 + e2 + e3);
        float ov = (e0 * vs[0][h * 64 + d] + e1 * vs[1][h * 64 + d] +
                    e2 * vs[2][h * 64 + d] + e3 * vs[3][h * 64 + d]) * inv;
        o[(m * 8 + w * 4 + qi) * 256 + h * 64 + d] = f2bits(ov);
    }
}

extern "C" void kernel_launch(void* const* d_in, const int* in_sizes, int n_in,
                              void* d_out, int out_size, void* d_ws, size_t ws_size,
                              hipStream_t stream)
{
    const float* z         = (const float*)d_in[0];
    const float* ln1_g     = (const float*)d_in[1];
    const float* ln1_b     = (const float*)d_in[2];
    const float* Wx        = (const float*)d_in[3];
    const float* conv_w    = (const float*)d_in[4];
    const float* Wz        = (const float*)d_in[5];
    const float* Wb        = (const float*)d_in[6];
    const float* Wc        = (const float*)d_in[7];
    const float* Wdt       = (const float*)d_in[8];
    const float* dt_bias   = (const float*)d_in[9];
    const float* A_log     = (const float*)d_in[10];
    const float* theta     = (const float*)d_in[11];
    const float* D_skip    = (const float*)d_in[12];
    const float* mimo_U    = (const float*)d_in[13];
    const float* mimo_V    = (const float*)d_in[14];
    const float* Wout      = (const float*)d_in[15];
    const float* ln2_g     = (const float*)d_in[16];
    const float* ln2_b     = (const float*)d_in[17];
    const float* attn_in_w = (const float*)d_in[18];
    const float* attn_in_b = (const float*)d_in[19];
    const float* attn_out_w= (const float*)d_in[20];
    const float* attn_out_b= (const float*)d_in[21];
    const float* ln3_g     = (const float*)d_in[22];
    const float* ln3_b     = (const float*)d_in[23];
    const float* Wg        = (const float*)d_in[24];
    const float* Wu        = (const float*)d_in[25];
    const float* Wd        = (const float*)d_in[26];

    float* W = (float*)d_ws;
    unsigned short* wts = (unsigned short*)W;
    unsigned short* ub  = (unsigned short*)(W + OFF_UB);
    unsigned short* x2b = (unsigned short*)(W + OFF_X2B);
    unsigned short* bmb = (unsigned short*)(W + OFF_BMB);
    unsigned short* cmb = (unsigned short*)(W + OFF_CMB);
    float* dt  = W + OFF_DT;
    float* ar  = W + OFF_AR;
    float* ai  = W + OFF_AI;
    float* zg  = W + OFF_ZG;
    float* y   = W + OFF_Y;
    float* x32 = W + OFF_SH2;           // x then Bm32 share
    float* bm32= W + OFF_SH2;
    float* z2  = W + OFF_Z2;
    unsigned short* ygb = (unsigned short*)(W + OFF_YGB);
    float* yout = W + OFF_YOUT;
    float* z1   = W + OFF_Z1;
    unsigned short* znb = (unsigned short*)(W + OFF_ZNB);
    unsigned short* ob  = (unsigned short*)(W + OFF_OB);
    float* t0   = W + OFF_T0;
    float* qkv  = W + OFF_QKV;
    unsigned short* zfb = (unsigned short*)(W + OFF_ZFB);
    unsigned short* sgb = (unsigned short*)(W + OFF_SGB);
    unsigned short* ggb = (unsigned short*)(W + OFF_GGB);

    // weight prep (every call; idempotent)
    prep_w<<<5888, 256, 0, stream>>>(Wx, Wb, Wc, Wz, Wout, attn_in_w, attn_out_w,
                                     Wg, Wu, Wd, wts);
    // ---------------- (a) intra-band Mamba3 ----------------
    ln1_kernel<<<4096, 256, 0, stream>>>(z, ln1_g, ln1_b, ub);
    mfma_gemm<<<dim3(2, 32), 256, 0, stream>>>(ub, wts + W_X, nullptr, nullptr, x32, 256, 256, 0, 0);
    conv_silu_kernel<<<4096, 256, 0, stream>>>(x32, conv_w, x2b);
    dt_small<<<4096, 64, 0, stream>>>(ub, Wdt, dt);
    dtprep_kernel<<<64, 256, 0, stream>>>(dt, ar, ai, dt_bias, A_log, theta);
    mfma_gemm<<<dim3(4, 32), 256, 0, stream>>>(ub, wts + W_B, nullptr, nullptr, bm32, 512, 256, 0, 0);
    mix_kernel<<<2048, 256, 0, stream>>>(bm32, mimo_U, mimo_V, bmb);
    mfma_gemm<<<dim3(4, 32), 256, 0, stream>>>(ub, wts + W_C, nullptr, nullptr, cmb, 512, 256, 0, 1);
    mfma_gemm<<<dim3(2, 32), 256, 0, stream>>>(ub, wts + W_Z, nullptr, nullptr, zg, 256, 256, 1, 0);
    scan2_kernel<<<1024, 64, 0, stream>>>(x2b, bmb, cmb, dt, ar, ai, D_skip, y);
    mul_kernel<<<4096, 256, 0, stream>>>(y, zg, ygb);
    mfma_gemm<<<dim3(2, 32), 256, 0, stream>>>(ygb, wts + W_O, nullptr, nullptr, yout, 256, 256, 0, 0);
    addres_kernel<<<4096, 256, 0, stream>>>(z, yout, z1);
    // ---------------- (b) inter-band windowed attention ----------------
    ln_f32_kernel<<<4096, 256, 0, stream>>>(z1, ln2_g, ln2_b, znb);
    mfma_gemm<<<dim3(6, 32), 256, 0, stream>>>(znb, wts + W_QKV, attn_in_b, nullptr, qkv, 768, 256, 0, 0);
    attn_kernel<<<1024, 256, 0, stream>>>(qkv, ob);
    mfma_gemm<<<dim3(2, 32), 256, 0, stream>>>(ob, wts + W_AO, attn_out_b, nullptr, t0, 256, 256, 0, 0);
    add_kernel<<<4096, 256, 0, stream>>>(z1, t0, z2);
    // ---------------- (c) SwiGLU FFN ----------------
    ln_f32_kernel<<<4096, 256, 0, stream>>>(z2, ln3_g, ln3_b, zfb);
    mfma_gemm<<<dim3(8, 32), 256, 0, stream>>>(zfb, wts + W_G, nullptr, nullptr, sgb, 1024, 256, 1, 1);
    mfma_gemm<<<dim3(8, 32), 256, 0, stream>>>(zfb, wts + W_U, nullptr, sgb, ggb, 1024, 256, 0, 1);
    mfma_gemm<<<dim3(2, 32), 256, 0, stream>>>(ggb, wts + W_D, nullptr, nullptr, t0, 256, 1024, 0, 0);
    final_kernel<<<4096, 256, 0, stream>>>(z2, t0, (float*)d_out);
}